// Round 10
// baseline (84.382 us; speedup 1.0000x reference)
//
#include <hip/hip_runtime.h>

// IoU assigner: N anchors x M gts (3D, 6 coords). Outputs (concatenated, f32):
//   out[0:N]   labels (-1 ignore, 0 neg, gt_label pos)
//   out[N:7N]  assigned boxes (gt box if pos, else -1.0)
//
// Bit-exact vs numpy f32: __f*_rn intrinsics (no FMA contraction), op order
// mirrors the jnp reference; argmax ties: first index (strict > scan).
//
// Round-10 structure: 4 anchors/thread (streams at stride H=(N+3)/4, each
// keeping the 24B/lane coalescing), gt tile in LDS as float4 pairs
// (2x ds_read_b128 per g instead of 7x b32), UNFUSED override.
// KEY FINDING (R9): the fused ticket/override tail made hipcc demote loop
// live values to scratch (WRITE_SIZE +8-13MB spill writes, 145-190us).
// Unfused, the same 2-anchor body ran clean (VGPR=20, WRITE=13.7MB, 50us).
// This round scales the clean structure: LDS-pipe model 7.6 waves/CU x 128g
// x 24cyc ~= 10us; VALU ~13us -> main ~20-28us.
//
// ws layout: [0,1024) slots[128] u64.

#define MMAX 128

// One anchor-stream's IoU step vs gt g. glo={x0,y0,z0,x1} ghi={y1,z1,area,label}
#define IOU_CHAIN(X0, Y0, Z0, X1, Y1, Z1, AR, BEST, ARG, ENC)                  \
    {                                                                          \
        float cx = fmaxf(__fsub_rn(fminf(X1, glo.w), fmaxf(X0, glo.x)), 0.f);  \
        float cy = fmaxf(__fsub_rn(fminf(Y1, ghi.x), fmaxf(Y0, glo.y)), 0.f);  \
        float cz = fmaxf(__fsub_rn(fminf(Z1, ghi.y), fmaxf(Z0, glo.z)), 0.f);  \
        float inter = __fmul_rn(__fmul_rn(cx, cy), cz);                        \
        if (inter > 0.f) { /* ~0.3% of pairs */                                \
            float den = __fadd_rn(__fsub_rn(__fadd_rn(AR, ghi.z), inter), 1e-7f);\
            float iou = __fdiv_rn(inter, den);                                 \
            if (iou > BEST) { BEST = iou; ARG = g; }                           \
            if (iou >= 0.3f) {                                                 \
                unsigned long long enc =                                       \
                    ((unsigned long long)__float_as_uint(iou) << 32) |         \
                    (unsigned long long)(ENC);                                 \
                atomicMax(&lsl[g], enc);                                       \
            }                                                                  \
        }                                                                      \
    }

template <int MC>
__global__ __launch_bounds__(256) void iou_main(
    const float* __restrict__ bx, const float* __restrict__ gt,
    const int* __restrict__ gl,
    float* __restrict__ out_lab, float* __restrict__ out_bb,
    unsigned long long* __restrict__ slots,
    int N, int Mrt)
{
    const int M = MC ? MC : Mrt;
    const int tid = threadIdx.x;

    // ---- stage gt boxes + area + label into LDS float4 pairs; zero slots ----
    __shared__ float4 gb4[MMAX * 2];  // [2g]={x0,y0,z0,x1} [2g+1]={y1,z1,area,label}
    __shared__ unsigned long long lsl[MMAX];
    if (tid < M) {
        const float* gp = gt + (size_t)tid * 6;
        float x0 = gp[0], y0 = gp[1], z0 = gp[2];
        float x1 = gp[3], y1 = gp[4], z1 = gp[5];
        float area = __fmul_rn(__fmul_rn(__fsub_rn(x1, x0), __fsub_rn(y1, y0)),
                               __fsub_rn(z1, z0));
        gb4[2 * tid]     = make_float4(x0, y0, z0, x1);
        gb4[2 * tid + 1] = make_float4(y1, z1, area, (float)gl[tid]);
    }
    if (tid < MMAX) lsl[tid] = 0ULL;
    __syncthreads();

    // ---- four anchors per thread at stride H (R1/R9-style guarded loads) ----
    const int H = (N + 3) >> 2;
    const int a = blockIdx.x * 256 + tid;
    const int b = a + H;
    const int c = a + 2 * H;
    const int d = a + 3 * H;
    const bool va = (a < H);           // H <= N so a < N too
    const bool vb = va && (b < N);
    const bool vc = va && (c < N);
    const bool vd = va && (d < N);

    float ax0 = 0.f, ay0 = 0.f, az0 = 0.f, ax1 = 0.f, ay1 = 0.f, az1 = 0.f;
    if (va) { const float* p = bx + (size_t)a * 6;
        ax0 = p[0]; ay0 = p[1]; az0 = p[2]; ax1 = p[3]; ay1 = p[4]; az1 = p[5]; }
    float bx0 = 0.f, by0 = 0.f, bz0 = 0.f, bx1 = 0.f, by1 = 0.f, bz1 = 0.f;
    if (vb) { const float* p = bx + (size_t)b * 6;
        bx0 = p[0]; by0 = p[1]; bz0 = p[2]; bx1 = p[3]; by1 = p[4]; bz1 = p[5]; }
    float cx0 = 0.f, cy0 = 0.f, cz0 = 0.f, cx1 = 0.f, cy1 = 0.f, cz1 = 0.f;
    if (vc) { const float* p = bx + (size_t)c * 6;
        cx0 = p[0]; cy0 = p[1]; cz0 = p[2]; cx1 = p[3]; cy1 = p[4]; cz1 = p[5]; }
    float dx0 = 0.f, dy0 = 0.f, dz0 = 0.f, dx1 = 0.f, dy1 = 0.f, dz1 = 0.f;
    if (vd) { const float* p = bx + (size_t)d * 6;
        dx0 = p[0]; dy0 = p[1]; dz0 = p[2]; dx1 = p[3]; dy1 = p[4]; dz1 = p[5]; }

    const float a1a = __fmul_rn(__fmul_rn(__fsub_rn(ax1, ax0),
                       __fsub_rn(ay1, ay0)), __fsub_rn(az1, az0));
    const float a1b = __fmul_rn(__fmul_rn(__fsub_rn(bx1, bx0),
                       __fsub_rn(by1, by0)), __fsub_rn(bz1, bz0));
    const float a1c = __fmul_rn(__fmul_rn(__fsub_rn(cx1, cx0),
                       __fsub_rn(cy1, cy0)), __fsub_rn(cz1, cz0));
    const float a1d = __fmul_rn(__fmul_rn(__fsub_rn(dx1, dx0),
                       __fsub_rn(dy1, dy0)), __fsub_rn(dz1, dz0));

    const unsigned encA = 0xFFFFFFFFu - (unsigned)a;   // loop-invariant
    const unsigned encB = 0xFFFFFFFFu - (unsigned)b;
    const unsigned encC = 0xFFFFFFFFu - (unsigned)c;
    const unsigned encD = 0xFFFFFFFFu - (unsigned)d;

    // best=0: iou==0 never strict-beats it (matches jnp.argmax first-index,
    // all-zero row -> argmax 0).
    float bestA = 0.f, bestB = 0.f, bestC = 0.f, bestD = 0.f;
    int   argA = 0,    argB = 0,    argC = 0,    argD = 0;

    for (int g = 0; g < M; ++g) {
        const float4 glo = gb4[2 * g];       // ds_read_b128 broadcast
        const float4 ghi = gb4[2 * g + 1];
        IOU_CHAIN(ax0, ay0, az0, ax1, ay1, az1, a1a, bestA, argA, encA)
        IOU_CHAIN(bx0, by0, bz0, bx1, by1, bz1, a1b, bestB, argB, encB)
        IOU_CHAIN(cx0, cy0, cz0, cx1, cy1, cz1, a1c, bestC, argC, encC)
        IOU_CHAIN(dx0, dy0, dz0, dx1, dy1, dz1, a1d, bestD, argD, encD)
    }

    // ---- epilogue: labels + boxes, R9-style scalar LDS reads/writes ----
    const float* gbf = (const float*)gb4;    // flat: [8g+0..5]=box, +6=area, +7=label
    if (va) {
        float lab;
        if (bestA >= 0.7f) lab = gbf[8 * argA + 7];
        else               lab = (bestA < 0.3f) ? 0.f : -1.f;
        out_lab[a] = lab;
        float* ob = out_bb + (size_t)a * 6;
        if (bestA >= 0.7f) {
            ob[0] = gbf[8*argA+0]; ob[1] = gbf[8*argA+1]; ob[2] = gbf[8*argA+2];
            ob[3] = gbf[8*argA+3]; ob[4] = gbf[8*argA+4]; ob[5] = gbf[8*argA+5];
        } else {
            ob[0] = -1.f; ob[1] = -1.f; ob[2] = -1.f;
            ob[3] = -1.f; ob[4] = -1.f; ob[5] = -1.f;
        }
    }
    if (vb) {
        float lab;
        if (bestB >= 0.7f) lab = gbf[8 * argB + 7];
        else               lab = (bestB < 0.3f) ? 0.f : -1.f;
        out_lab[b] = lab;
        float* ob = out_bb + (size_t)b * 6;
        if (bestB >= 0.7f) {
            ob[0] = gbf[8*argB+0]; ob[1] = gbf[8*argB+1]; ob[2] = gbf[8*argB+2];
            ob[3] = gbf[8*argB+3]; ob[4] = gbf[8*argB+4]; ob[5] = gbf[8*argB+5];
        } else {
            ob[0] = -1.f; ob[1] = -1.f; ob[2] = -1.f;
            ob[3] = -1.f; ob[4] = -1.f; ob[5] = -1.f;
        }
    }
    if (vc) {
        float lab;
        if (bestC >= 0.7f) lab = gbf[8 * argC + 7];
        else               lab = (bestC < 0.3f) ? 0.f : -1.f;
        out_lab[c] = lab;
        float* ob = out_bb + (size_t)c * 6;
        if (bestC >= 0.7f) {
            ob[0] = gbf[8*argC+0]; ob[1] = gbf[8*argC+1]; ob[2] = gbf[8*argC+2];
            ob[3] = gbf[8*argC+3]; ob[4] = gbf[8*argC+4]; ob[5] = gbf[8*argC+5];
        } else {
            ob[0] = -1.f; ob[1] = -1.f; ob[2] = -1.f;
            ob[3] = -1.f; ob[4] = -1.f; ob[5] = -1.f;
        }
    }
    if (vd) {
        float lab;
        if (bestD >= 0.7f) lab = gbf[8 * argD + 7];
        else               lab = (bestD < 0.3f) ? 0.f : -1.f;
        out_lab[d] = lab;
        float* ob = out_bb + (size_t)d * 6;
        if (bestD >= 0.7f) {
            ob[0] = gbf[8*argD+0]; ob[1] = gbf[8*argD+1]; ob[2] = gbf[8*argD+2];
            ob[3] = gbf[8*argD+3]; ob[4] = gbf[8*argD+4]; ob[5] = gbf[8*argD+5];
        } else {
            ob[0] = -1.f; ob[1] = -1.f; ob[2] = -1.f;
            ob[3] = -1.f; ob[4] = -1.f; ob[5] = -1.f;
        }
    }

    // ---- flush per-block per-gt maxima to global slots ----
    __syncthreads();
    for (int g = tid; g < M; g += 256) {
        unsigned long long v = lsl[g];
        if (v) atomicMax(&slots[g], v);
    }
}

// Low-quality override (separate dispatch — fusing this tail provably makes
// hipcc spill the main loop's live set, R3-R9): for each gt with a nonzero
// slot (column max >= 0.3), its argmax anchor gets that gt; when several gts
// pick the same anchor the LARGEST gt index wins (.at[].max scatter).
__global__ __launch_bounds__(MMAX) void iou_override(
    const float* __restrict__ gt, const int* __restrict__ gl,
    const unsigned long long* __restrict__ slots,
    float* __restrict__ out_lab, float* __restrict__ out_bb, int M)
{
    __shared__ int s_anchor[MMAX];
    __shared__ int s_cand[MMAX];
    const int i = threadIdx.x;

    int anchor = -1, cand = 0;
    if (i < M) {
        unsigned long long v = slots[i];
        if (v != 0ULL) {               // gt_iou_max >= 0.3 (gated at insert)
            anchor = (int)(0xFFFFFFFFu - (unsigned)(v & 0xFFFFFFFFu));
            cand   = i + 1;
        }
    }
    s_anchor[i] = anchor;
    s_cand[i]   = cand;
    __syncthreads();

    if (cand > 0) {
        bool win = true;
        for (int j = 0; j < M; ++j)
            if (s_cand[j] > cand && s_anchor[j] == anchor) { win = false; break; }
        if (win) {
            out_lab[anchor] = (float)gl[i];
            float* ob = out_bb + (size_t)anchor * 6;
            const float* gp = gt + (size_t)i * 6;
            ob[0] = gp[0]; ob[1] = gp[1]; ob[2] = gp[2];
            ob[3] = gp[3]; ob[4] = gp[4]; ob[5] = gp[5];
        }
    }
}

extern "C" void kernel_launch(void* const* d_in, const int* in_sizes, int n_in,
                              void* d_out, int out_size, void* d_ws, size_t ws_size,
                              hipStream_t stream)
{
    const float* bx = (const float*)d_in[0];
    const float* gt = (const float*)d_in[1];
    const int*   gl = (const int*)d_in[2];
    const int N = in_sizes[0] / 6;
    int M = in_sizes[1] / 6;
    if (M > MMAX) M = MMAX;

    float* out_lab = (float*)d_out;
    float* out_bb  = (float*)d_out + N;

    unsigned long long* slots = (unsigned long long*)d_ws;

    // slots MUST be re-zeroed every call (ws is poisoned once, not re-poisoned
    // between timed replays).
    hipMemsetAsync(d_ws, 0, MMAX * 8, stream);

    const int H = (N + 3) / 4;
    const int nblocks = (H + 255) / 256;

    if (M == MMAX) {
        hipLaunchKernelGGL(iou_main<MMAX>, dim3(nblocks), dim3(256), 0, stream,
                           bx, gt, gl, out_lab, out_bb, slots, N, M);
    } else {
        hipLaunchKernelGGL(iou_main<0>, dim3(nblocks), dim3(256), 0, stream,
                           bx, gt, gl, out_lab, out_bb, slots, N, M);
    }
    hipLaunchKernelGGL(iou_override, dim3(1), dim3(MMAX), 0, stream,
                       gt, gl, slots, out_lab, out_bb, M);
}

// Round 11
// 70.984 us; speedup vs baseline: 1.1888x; 1.1888x over previous
//
#include <hip/hip_runtime.h>

// IoU assigner: N anchors x M gts (3D, 6 coords). Outputs (concatenated, f32):
//   out[0:N]   labels (-1 ignore, 0 neg, gt_label pos)
//   out[N:7N]  assigned boxes (gt box if pos, else -1.0)
//
// Bit-exact vs numpy f32: __f*_rn intrinsics (no FMA contraction), op order
// mirrors the jnp reference; argmax ties: first index (strict > scan).
//
// Round-11: merge of the two proven-clean features:
//   - 2 anchors/thread at stride H=(N+1)/2  (R9: best wave count, 50.5us)
//   - gt tile as LDS float4 pairs, 2x ds_read_b128/iter  (R10: 24 cyc vs 40)
// Design-space data: 1 anchor=LDS-bound 65us; 4 anchors=latency-bound 64us
// (1.4 waves/SIMD); 2 anchors balances. LDS model: 15.3 waves/CU x 128 x 24
// = 47K cyc/CU ~= 20us; VALU ~14us; with 3.8 blocks/CU latency mostly hidden.
// UNFUSED override (fusing the tail provably triggers scratch demotion of
// the loop live set: R3-R8 all spilled, WRITE_SIZE +8-13MB; R9/R10 clean).
//
// ws layout: [0,1024) slots[128] u64.

#define MMAX 128

// One anchor-stream's IoU step vs gt g. glo={x0,y0,z0,x1} ghi={y1,z1,area,label}
#define IOU_CHAIN(X0, Y0, Z0, X1, Y1, Z1, AR, BEST, ARG, ENC)                  \
    {                                                                          \
        float cx = fmaxf(__fsub_rn(fminf(X1, glo.w), fmaxf(X0, glo.x)), 0.f);  \
        float cy = fmaxf(__fsub_rn(fminf(Y1, ghi.x), fmaxf(Y0, glo.y)), 0.f);  \
        float cz = fmaxf(__fsub_rn(fminf(Z1, ghi.y), fmaxf(Z0, glo.z)), 0.f);  \
        float inter = __fmul_rn(__fmul_rn(cx, cy), cz);                        \
        if (inter > 0.f) { /* ~0.3% of pairs */                                \
            float den = __fadd_rn(__fsub_rn(__fadd_rn(AR, ghi.z), inter), 1e-7f);\
            float iou = __fdiv_rn(inter, den);                                 \
            if (iou > BEST) { BEST = iou; ARG = g; }                           \
            if (iou >= 0.3f) {                                                 \
                unsigned long long enc =                                       \
                    ((unsigned long long)__float_as_uint(iou) << 32) |         \
                    (unsigned long long)(ENC);                                 \
                atomicMax(&lsl[g], enc);                                       \
            }                                                                  \
        }                                                                      \
    }

template <int MC>
__global__ __launch_bounds__(256) void iou_main(
    const float* __restrict__ bx, const float* __restrict__ gt,
    const int* __restrict__ gl,
    float* __restrict__ out_lab, float* __restrict__ out_bb,
    unsigned long long* __restrict__ slots,
    int N, int Mrt)
{
    const int M = MC ? MC : Mrt;
    const int tid = threadIdx.x;

    // ---- stage gt boxes + area + label into LDS float4 pairs; zero slots ----
    __shared__ float4 gb4[MMAX * 2];  // [2g]={x0,y0,z0,x1} [2g+1]={y1,z1,area,label}
    __shared__ unsigned long long lsl[MMAX];
    if (tid < M) {
        const float* gp = gt + (size_t)tid * 6;
        float x0 = gp[0], y0 = gp[1], z0 = gp[2];
        float x1 = gp[3], y1 = gp[4], z1 = gp[5];
        float area = __fmul_rn(__fmul_rn(__fsub_rn(x1, x0), __fsub_rn(y1, y0)),
                               __fsub_rn(z1, z0));
        gb4[2 * tid]     = make_float4(x0, y0, z0, x1);
        gb4[2 * tid + 1] = make_float4(y1, z1, area, (float)gl[tid]);
    }
    if (tid < MMAX) lsl[tid] = 0ULL;
    __syncthreads();

    // ---- two anchors per thread: a in [0,H), b = a + H (guarded loads) ----
    const int H = (N + 1) >> 1;
    const int a = blockIdx.x * 256 + tid;
    const int b = a + H;
    const bool va = (a < H);          // a < H <= N
    const bool vb = va && (b < N);

    float ax0 = 0.f, ay0 = 0.f, az0 = 0.f, ax1 = 0.f, ay1 = 0.f, az1 = 0.f;
    if (va) { const float* p = bx + (size_t)a * 6;
        ax0 = p[0]; ay0 = p[1]; az0 = p[2]; ax1 = p[3]; ay1 = p[4]; az1 = p[5]; }
    float bx0 = 0.f, by0 = 0.f, bz0 = 0.f, bx1 = 0.f, by1 = 0.f, bz1 = 0.f;
    if (vb) { const float* p = bx + (size_t)b * 6;
        bx0 = p[0]; by0 = p[1]; bz0 = p[2]; bx1 = p[3]; by1 = p[4]; bz1 = p[5]; }

    const float a1a = __fmul_rn(__fmul_rn(__fsub_rn(ax1, ax0),
                       __fsub_rn(ay1, ay0)), __fsub_rn(az1, az0));
    const float a1b = __fmul_rn(__fmul_rn(__fsub_rn(bx1, bx0),
                       __fsub_rn(by1, by0)), __fsub_rn(bz1, bz0));

    const unsigned encA = 0xFFFFFFFFu - (unsigned)a;   // loop-invariant
    const unsigned encB = 0xFFFFFFFFu - (unsigned)b;

    // best=0: iou==0 never strict-beats it (matches jnp.argmax first-index,
    // all-zero row -> argmax 0).
    float bestA = 0.f, bestB = 0.f;
    int   argA = 0,    argB = 0;

    for (int g = 0; g < M; ++g) {
        const float4 glo = gb4[2 * g];       // ds_read_b128 broadcast
        const float4 ghi = gb4[2 * g + 1];
        IOU_CHAIN(ax0, ay0, az0, ax1, ay1, az1, a1a, bestA, argA, encA)
        IOU_CHAIN(bx0, by0, bz0, bx1, by1, bz1, a1b, bestB, argB, encB)
    }

    // ---- epilogue: labels + boxes, scalar LDS reads/writes ----
    const float* gbf = (const float*)gb4;    // flat: [8g+0..5]=box, +6=area, +7=label
    if (va) {
        float lab;
        if (bestA >= 0.7f) lab = gbf[8 * argA + 7];
        else               lab = (bestA < 0.3f) ? 0.f : -1.f;
        out_lab[a] = lab;
        float* ob = out_bb + (size_t)a * 6;
        if (bestA >= 0.7f) {
            ob[0] = gbf[8*argA+0]; ob[1] = gbf[8*argA+1]; ob[2] = gbf[8*argA+2];
            ob[3] = gbf[8*argA+3]; ob[4] = gbf[8*argA+4]; ob[5] = gbf[8*argA+5];
        } else {
            ob[0] = -1.f; ob[1] = -1.f; ob[2] = -1.f;
            ob[3] = -1.f; ob[4] = -1.f; ob[5] = -1.f;
        }
    }
    if (vb) {
        float lab;
        if (bestB >= 0.7f) lab = gbf[8 * argB + 7];
        else               lab = (bestB < 0.3f) ? 0.f : -1.f;
        out_lab[b] = lab;
        float* ob = out_bb + (size_t)b * 6;
        if (bestB >= 0.7f) {
            ob[0] = gbf[8*argB+0]; ob[1] = gbf[8*argB+1]; ob[2] = gbf[8*argB+2];
            ob[3] = gbf[8*argB+3]; ob[4] = gbf[8*argB+4]; ob[5] = gbf[8*argB+5];
        } else {
            ob[0] = -1.f; ob[1] = -1.f; ob[2] = -1.f;
            ob[3] = -1.f; ob[4] = -1.f; ob[5] = -1.f;
        }
    }

    // ---- flush per-block per-gt maxima to global slots ----
    __syncthreads();
    for (int g = tid; g < M; g += 256) {
        unsigned long long v = lsl[g];
        if (v) atomicMax(&slots[g], v);
    }
}

// Low-quality override (separate dispatch — fusing this tail provably makes
// hipcc spill the main loop's live set, R3-R8): for each gt with a nonzero
// slot (column max >= 0.3), its argmax anchor gets that gt; when several gts
// pick the same anchor the LARGEST gt index wins (.at[].max scatter).
__global__ __launch_bounds__(MMAX) void iou_override(
    const float* __restrict__ gt, const int* __restrict__ gl,
    const unsigned long long* __restrict__ slots,
    float* __restrict__ out_lab, float* __restrict__ out_bb, int M)
{
    __shared__ int s_anchor[MMAX];
    __shared__ int s_cand[MMAX];
    const int i = threadIdx.x;

    int anchor = -1, cand = 0;
    if (i < M) {
        unsigned long long v = slots[i];
        if (v != 0ULL) {               // gt_iou_max >= 0.3 (gated at insert)
            anchor = (int)(0xFFFFFFFFu - (unsigned)(v & 0xFFFFFFFFu));
            cand   = i + 1;
        }
    }
    s_anchor[i] = anchor;
    s_cand[i]   = cand;
    __syncthreads();

    if (cand > 0) {
        bool win = true;
        for (int j = 0; j < M; ++j)
            if (s_cand[j] > cand && s_anchor[j] == anchor) { win = false; break; }
        if (win) {
            out_lab[anchor] = (float)gl[i];
            float* ob = out_bb + (size_t)anchor * 6;
            const float* gp = gt + (size_t)i * 6;
            ob[0] = gp[0]; ob[1] = gp[1]; ob[2] = gp[2];
            ob[3] = gp[3]; ob[4] = gp[4]; ob[5] = gp[5];
        }
    }
}

extern "C" void kernel_launch(void* const* d_in, const int* in_sizes, int n_in,
                              void* d_out, int out_size, void* d_ws, size_t ws_size,
                              hipStream_t stream)
{
    const float* bx = (const float*)d_in[0];
    const float* gt = (const float*)d_in[1];
    const int*   gl = (const int*)d_in[2];
    const int N = in_sizes[0] / 6;
    int M = in_sizes[1] / 6;
    if (M > MMAX) M = MMAX;

    float* out_lab = (float*)d_out;
    float* out_bb  = (float*)d_out + N;

    unsigned long long* slots = (unsigned long long*)d_ws;

    // slots MUST be re-zeroed every call (ws is poisoned once, not re-poisoned
    // between timed replays).
    hipMemsetAsync(d_ws, 0, MMAX * 8, stream);

    const int H = (N + 1) / 2;
    const int nblocks = (H + 255) / 256;

    if (M == MMAX) {
        hipLaunchKernelGGL(iou_main<MMAX>, dim3(nblocks), dim3(256), 0, stream,
                           bx, gt, gl, out_lab, out_bb, slots, N, M);
    } else {
        hipLaunchKernelGGL(iou_main<0>, dim3(nblocks), dim3(256), 0, stream,
                           bx, gt, gl, out_lab, out_bb, slots, N, M);
    }
    hipLaunchKernelGGL(iou_override, dim3(1), dim3(MMAX), 0, stream,
                       gt, gl, slots, out_lab, out_bb, M);
}

// Round 12
// 67.379 us; speedup vs baseline: 1.2524x; 1.0535x over previous
//
#include <hip/hip_runtime.h>

// IoU assigner: N anchors x M gts (3D, 6 coords). Outputs (concatenated, f32):
//   out[0:N]   labels (-1 ignore, 0 neg, gt_label pos)
//   out[N:7N]  assigned boxes (gt box if pos, else -1.0)
//
// Bit-exact vs numpy f32: __f*_rn intrinsics (no FMA contraction), op order
// mirrors the jnp reference; argmax ties: first index (strict > scan, and
// cross-chunk merge encodes (iou_bits<<32)|~g so max picks smallest g on ties).
//
// Round-12 structure: 2D decomposition. Each block: 256 anchors (64 lanes x
// 4 strides at H=(N+3)/4) x 4 gt-chunks (wave w -> gts [32w,32w+32)). All 4
// waves cover the SAME 256 anchors; per-anchor (best,arg) merged via 256 LDS
// u64 slots. Same total VALU + LDS traffic as R10's clean 4-anchor kernel,
// but 4x the waves (7812, SIMDs saturate at 8) and 1/4 the serial
// ds_read->compute chain per wave. R11 finding: 943 cyc/iter/wave wall at
// only 39% LDS / 32% VALU busy = latency-bound; this attacks the round-trip
// count directly.
// UNFUSED override (fusing that tail provably triggers scratch demotion,
// R3-R8: WRITE_SIZE +8-13MB spill writes).
//
// ws layout: [0,1024) slots[128] u64.

#define MMAX 128

// One anchor-stream's IoU step vs gt g. glo={x0,y0,z0,x1} ghi={y1,z1,area,label}
#define IOU_CHAIN(X0, Y0, Z0, X1, Y1, Z1, AR, BEST, ARG, ENC)                  \
    {                                                                          \
        float cx = fmaxf(__fsub_rn(fminf(X1, glo.w), fmaxf(X0, glo.x)), 0.f);  \
        float cy = fmaxf(__fsub_rn(fminf(Y1, ghi.x), fmaxf(Y0, glo.y)), 0.f);  \
        float cz = fmaxf(__fsub_rn(fminf(Z1, ghi.y), fmaxf(Z0, glo.z)), 0.f);  \
        float inter = __fmul_rn(__fmul_rn(cx, cy), cz);                        \
        if (inter > 0.f) { /* ~0.3% of pairs */                                \
            float den = __fadd_rn(__fsub_rn(__fadd_rn(AR, ghi.z), inter), 1e-7f);\
            float iou = __fdiv_rn(inter, den);                                 \
            if (iou > BEST) { BEST = iou; ARG = g; }                           \
            if (iou >= 0.3f) {                                                 \
                unsigned long long enc =                                       \
                    ((unsigned long long)__float_as_uint(iou) << 32) |         \
                    (unsigned long long)(ENC);                                 \
                atomicMax(&lsl[g], enc);                                       \
            }                                                                  \
        }                                                                      \
    }

template <int MC>
__global__ __launch_bounds__(256) void iou_main(
    const float* __restrict__ bx, const float* __restrict__ gt,
    const int* __restrict__ gl,
    float* __restrict__ out_lab, float* __restrict__ out_bb,
    unsigned long long* __restrict__ slots,
    int N, int Mrt)
{
    const int M = MC ? MC : Mrt;
    const int tid  = threadIdx.x;
    const int lane = tid & 63;
    const int wv   = tid >> 6;

    // ---- stage gt tile; zero per-gt and per-anchor LDS slots ----
    __shared__ float4 gb4[MMAX * 2];  // [2g]={x0,y0,z0,x1} [2g+1]={y1,z1,area,label}
    __shared__ unsigned long long lsl[MMAX];   // per-gt column max
    __shared__ unsigned long long asl[256];    // per-anchor (best,arg) merge
    if (tid < M) {
        const float* gp = gt + (size_t)tid * 6;
        float x0 = gp[0], y0 = gp[1], z0 = gp[2];
        float x1 = gp[3], y1 = gp[4], z1 = gp[5];
        float area = __fmul_rn(__fmul_rn(__fsub_rn(x1, x0), __fsub_rn(y1, y0)),
                               __fsub_rn(z1, z0));
        gb4[2 * tid]     = make_float4(x0, y0, z0, x1);
        gb4[2 * tid + 1] = make_float4(y1, z1, area, (float)gl[tid]);
    }
    if (tid < MMAX) lsl[tid] = 0ULL;
    asl[tid] = 0ULL;
    __syncthreads();

    // ---- four anchors per LANE at stride H; all 4 waves share them ----
    const int H = (N + 3) >> 2;
    const int base = blockIdx.x * 64 + lane;
    const int a = base, b = base + H, c = base + 2 * H, d = base + 3 * H;
    const bool va = (base < H);
    const bool vb = va && (b < N);
    const bool vc = va && (c < N);
    const bool vd = va && (d < N);

    float ax0 = 0.f, ay0 = 0.f, az0 = 0.f, ax1 = 0.f, ay1 = 0.f, az1 = 0.f;
    if (va) { const float* p = bx + (size_t)a * 6;
        ax0 = p[0]; ay0 = p[1]; az0 = p[2]; ax1 = p[3]; ay1 = p[4]; az1 = p[5]; }
    float bx0 = 0.f, by0 = 0.f, bz0 = 0.f, bx1 = 0.f, by1 = 0.f, bz1 = 0.f;
    if (vb) { const float* p = bx + (size_t)b * 6;
        bx0 = p[0]; by0 = p[1]; bz0 = p[2]; bx1 = p[3]; by1 = p[4]; bz1 = p[5]; }
    float cx0 = 0.f, cy0 = 0.f, cz0 = 0.f, cx1 = 0.f, cy1 = 0.f, cz1 = 0.f;
    if (vc) { const float* p = bx + (size_t)c * 6;
        cx0 = p[0]; cy0 = p[1]; cz0 = p[2]; cx1 = p[3]; cy1 = p[4]; cz1 = p[5]; }
    float dx0 = 0.f, dy0 = 0.f, dz0 = 0.f, dx1 = 0.f, dy1 = 0.f, dz1 = 0.f;
    if (vd) { const float* p = bx + (size_t)d * 6;
        dx0 = p[0]; dy0 = p[1]; dz0 = p[2]; dx1 = p[3]; dy1 = p[4]; dz1 = p[5]; }

    const float a1a = __fmul_rn(__fmul_rn(__fsub_rn(ax1, ax0),
                       __fsub_rn(ay1, ay0)), __fsub_rn(az1, az0));
    const float a1b = __fmul_rn(__fmul_rn(__fsub_rn(bx1, bx0),
                       __fsub_rn(by1, by0)), __fsub_rn(bz1, bz0));
    const float a1c = __fmul_rn(__fmul_rn(__fsub_rn(cx1, cx0),
                       __fsub_rn(cy1, cy0)), __fsub_rn(cz1, cz0));
    const float a1d = __fmul_rn(__fmul_rn(__fsub_rn(dx1, dx0),
                       __fsub_rn(dy1, dy0)), __fsub_rn(dz1, dz0));

    const unsigned encA = 0xFFFFFFFFu - (unsigned)a;   // loop-invariant
    const unsigned encB = 0xFFFFFFFFu - (unsigned)b;
    const unsigned encC = 0xFFFFFFFFu - (unsigned)c;
    const unsigned encD = 0xFFFFFFFFu - (unsigned)d;

    // ---- this wave's gt chunk ----
    const int chunk = (M + 3) >> 2;
    const int g0 = wv * chunk;
    const int g1 = (g0 + chunk < M) ? (g0 + chunk) : M;

    float bestA = 0.f, bestB = 0.f, bestC = 0.f, bestD = 0.f;
    int   argA = g0,   argB = g0,   argC = g0,   argD = g0;

    for (int g = g0; g < g1; ++g) {
        const float4 glo = gb4[2 * g];       // ds_read_b128 broadcast
        const float4 ghi = gb4[2 * g + 1];
        IOU_CHAIN(ax0, ay0, az0, ax1, ay1, az1, a1a, bestA, argA, encA)
        IOU_CHAIN(bx0, by0, bz0, bx1, by1, bz1, a1b, bestB, argB, encB)
        IOU_CHAIN(cx0, cy0, cz0, cx1, cy1, cz1, a1c, bestC, argC, encC)
        IOU_CHAIN(dx0, dy0, dz0, dx1, dy1, dz1, a1d, bestD, argD, encD)
    }

    // ---- merge per-anchor chunk results: (iou_bits<<32)|~g, max = best iou,
    //      smallest g on ties (first-index argmax across the full 0..M-1) ----
    if (va) atomicMax(&asl[0 * 64 + lane],
        ((unsigned long long)__float_as_uint(bestA) << 32) |
        (unsigned long long)(0xFFFFFFFFu - (unsigned)argA));
    if (vb) atomicMax(&asl[1 * 64 + lane],
        ((unsigned long long)__float_as_uint(bestB) << 32) |
        (unsigned long long)(0xFFFFFFFFu - (unsigned)argB));
    if (vc) atomicMax(&asl[2 * 64 + lane],
        ((unsigned long long)__float_as_uint(bestC) << 32) |
        (unsigned long long)(0xFFFFFFFFu - (unsigned)argC));
    if (vd) atomicMax(&asl[3 * 64 + lane],
        ((unsigned long long)__float_as_uint(bestD) << 32) |
        (unsigned long long)(0xFFFFFFFFu - (unsigned)argD));
    __syncthreads();

    // ---- flush per-gt maxima to global slots ----
    if (tid < M) {
        unsigned long long v = lsl[tid];
        if (v) atomicMax(&slots[tid], v);
    }

    // ---- epilogue: thread tid owns anchor slot tid ----
    {
        const int k = tid >> 6, l = tid & 63;
        const int sb = blockIdx.x * 64 + l;
        const int anchor = sb + k * H;
        if (sb < H && anchor < N) {
            const unsigned long long v = asl[tid];
            const float best = __uint_as_float((unsigned)(v >> 32));
            const int garg = (int)(0xFFFFFFFFu - (unsigned)(v & 0xFFFFFFFFu));
            const float* gbf = (const float*)gb4;   // [8g+0..5]=box +6=area +7=label
            float lab;
            if (best >= 0.7f) lab = gbf[8 * garg + 7];
            else              lab = (best < 0.3f) ? 0.f : -1.f;
            out_lab[anchor] = lab;
            float* ob = out_bb + (size_t)anchor * 6;
            if (best >= 0.7f) {
                ob[0] = gbf[8*garg+0]; ob[1] = gbf[8*garg+1]; ob[2] = gbf[8*garg+2];
                ob[3] = gbf[8*garg+3]; ob[4] = gbf[8*garg+4]; ob[5] = gbf[8*garg+5];
            } else {
                ob[0] = -1.f; ob[1] = -1.f; ob[2] = -1.f;
                ob[3] = -1.f; ob[4] = -1.f; ob[5] = -1.f;
            }
        }
    }
}

// Low-quality override (separate dispatch — fusing this tail provably makes
// hipcc spill the main loop's live set, R3-R8): for each gt with a nonzero
// slot (column max >= 0.3), its argmax anchor gets that gt; when several gts
// pick the same anchor the LARGEST gt index wins (.at[].max scatter).
__global__ __launch_bounds__(MMAX) void iou_override(
    const float* __restrict__ gt, const int* __restrict__ gl,
    const unsigned long long* __restrict__ slots,
    float* __restrict__ out_lab, float* __restrict__ out_bb, int M)
{
    __shared__ int s_anchor[MMAX];
    __shared__ int s_cand[MMAX];
    const int i = threadIdx.x;

    int anchor = -1, cand = 0;
    if (i < M) {
        unsigned long long v = slots[i];
        if (v != 0ULL) {               // gt_iou_max >= 0.3 (gated at insert)
            anchor = (int)(0xFFFFFFFFu - (unsigned)(v & 0xFFFFFFFFu));
            cand   = i + 1;
        }
    }
    s_anchor[i] = anchor;
    s_cand[i]   = cand;
    __syncthreads();

    if (cand > 0) {
        bool win = true;
        for (int j = 0; j < M; ++j)
            if (s_cand[j] > cand && s_anchor[j] == anchor) { win = false; break; }
        if (win) {
            out_lab[anchor] = (float)gl[i];
            float* ob = out_bb + (size_t)anchor * 6;
            const float* gp = gt + (size_t)i * 6;
            ob[0] = gp[0]; ob[1] = gp[1]; ob[2] = gp[2];
            ob[3] = gp[3]; ob[4] = gp[4]; ob[5] = gp[5];
        }
    }
}

extern "C" void kernel_launch(void* const* d_in, const int* in_sizes, int n_in,
                              void* d_out, int out_size, void* d_ws, size_t ws_size,
                              hipStream_t stream)
{
    const float* bx = (const float*)d_in[0];
    const float* gt = (const float*)d_in[1];
    const int*   gl = (const int*)d_in[2];
    const int N = in_sizes[0] / 6;
    int M = in_sizes[1] / 6;
    if (M > MMAX) M = MMAX;

    float* out_lab = (float*)d_out;
    float* out_bb  = (float*)d_out + N;

    unsigned long long* slots = (unsigned long long*)d_ws;

    // slots MUST be re-zeroed every call (ws is poisoned once, not re-poisoned
    // between timed replays).
    hipMemsetAsync(d_ws, 0, MMAX * 8, stream);

    const int H = (N + 3) / 4;
    const int nblocks = (H + 63) / 64;

    if (M == MMAX) {
        hipLaunchKernelGGL(iou_main<MMAX>, dim3(nblocks), dim3(256), 0, stream,
                           bx, gt, gl, out_lab, out_bb, slots, N, M);
    } else {
        hipLaunchKernelGGL(iou_main<0>, dim3(nblocks), dim3(256), 0, stream,
                           bx, gt, gl, out_lab, out_bb, slots, N, M);
    }
    hipLaunchKernelGGL(iou_override, dim3(1), dim3(MMAX), 0, stream,
                       gt, gl, slots, out_lab, out_bb, M);
}

// Round 13
// 64.015 us; speedup vs baseline: 1.3182x; 1.0525x over previous
//
#include <hip/hip_runtime.h>

// IoU assigner: N anchors x M gts (3D, 6 coords). Outputs (concatenated, f32):
//   out[0:N]   labels (-1 ignore, 0 neg, gt_label pos)
//   out[N:7N]  assigned boxes (gt box if pos, else -1.0)
//
// Bit-exact vs numpy f32: __f*_rn intrinsics (no FMA contraction), op order
// mirrors the jnp reference; argmax ties: first index (strict > scan; the
// cross-chunk merge encodes (iou_bits<<32)|~g so max picks smallest g).
//
// Round-13: R12's 2D structure (256 anchors x 4 gt-chunk waves per block,
// per-anchor merge via 256 LDS u64 slots — clean codegen, 46.7us) with the
// g-loop manually unrolled x4: 8 back-to-back ds_read_b128 per iteration,
// then 16 register-resident IoU chains. Quarters the ds_read->waitcnt->
// compute round trips per wave (R12 diagnosis: 112K cyc/CU wall vs ~34K
// VALU + ~12K LDS issue = latency on the per-gt LDS round trip).
// UNFUSED override + explicit memset (fusing the override tail provably
// makes hipcc demote loop state to scratch: R3-R8, WRITE_SIZE +8-13MB).
//
// ws layout: [0,1024) slots[128] u64.

#define MMAX 128

// One (gt, anchor-chain) IoU step on registers.
#define IOU_ONE(GLO, GHI, G, X0, Y0, Z0, X1, Y1, Z1, AR, BEST, ARG, ENC)       \
    {                                                                          \
        float cx = fmaxf(__fsub_rn(fminf(X1, GLO.w), fmaxf(X0, GLO.x)), 0.f);  \
        float cy = fmaxf(__fsub_rn(fminf(Y1, GHI.x), fmaxf(Y0, GLO.y)), 0.f);  \
        float cz = fmaxf(__fsub_rn(fminf(Z1, GHI.y), fmaxf(Z0, GLO.z)), 0.f);  \
        float inter = __fmul_rn(__fmul_rn(cx, cy), cz);                        \
        if (inter > 0.f) { /* ~0.3% of pairs */                                \
            float den = __fadd_rn(__fsub_rn(__fadd_rn(AR, GHI.z), inter), 1e-7f);\
            float iou = __fdiv_rn(inter, den);                                 \
            if (iou > BEST) { BEST = iou; ARG = (G); }                         \
            if (iou >= 0.3f) {                                                 \
                unsigned long long enc =                                       \
                    ((unsigned long long)__float_as_uint(iou) << 32) |         \
                    (unsigned long long)(ENC);                                 \
                atomicMax(&lsl[(G)], enc);                                     \
            }                                                                  \
        }                                                                      \
    }

// All 4 anchor chains vs one gt.
#define IOU_G(GLO, GHI, G)                                                     \
    IOU_ONE(GLO, GHI, G, ax0, ay0, az0, ax1, ay1, az1, a1a, bestA, argA, encA) \
    IOU_ONE(GLO, GHI, G, bx0, by0, bz0, bx1, by1, bz1, a1b, bestB, argB, encB) \
    IOU_ONE(GLO, GHI, G, cx0, cy0, cz0, cx1, cy1, cz1, a1c, bestC, argC, encC) \
    IOU_ONE(GLO, GHI, G, dx0, dy0, dz0, dx1, dy1, dz1, a1d, bestD, argD, encD)

template <int MC>
__global__ __launch_bounds__(256) void iou_main(
    const float* __restrict__ bx, const float* __restrict__ gt,
    const int* __restrict__ gl,
    float* __restrict__ out_lab, float* __restrict__ out_bb,
    unsigned long long* __restrict__ slots,
    int N, int Mrt)
{
    const int M = MC ? MC : Mrt;
    const int tid  = threadIdx.x;
    const int lane = tid & 63;
    const int wv   = tid >> 6;

    // ---- stage gt tile; zero per-gt and per-anchor LDS slots ----
    __shared__ float4 gb4[MMAX * 2];  // [2g]={x0,y0,z0,x1} [2g+1]={y1,z1,area,label}
    __shared__ unsigned long long lsl[MMAX];   // per-gt column max
    __shared__ unsigned long long asl[256];    // per-anchor (best,arg) merge
    if (tid < M) {
        const float* gp = gt + (size_t)tid * 6;
        float x0 = gp[0], y0 = gp[1], z0 = gp[2];
        float x1 = gp[3], y1 = gp[4], z1 = gp[5];
        float area = __fmul_rn(__fmul_rn(__fsub_rn(x1, x0), __fsub_rn(y1, y0)),
                               __fsub_rn(z1, z0));
        gb4[2 * tid]     = make_float4(x0, y0, z0, x1);
        gb4[2 * tid + 1] = make_float4(y1, z1, area, (float)gl[tid]);
    }
    if (tid < MMAX) lsl[tid] = 0ULL;
    asl[tid] = 0ULL;
    __syncthreads();

    // ---- four anchors per LANE at stride H; all 4 waves share them ----
    const int H = (N + 3) >> 2;
    const int base = blockIdx.x * 64 + lane;
    const int a = base, b = base + H, c = base + 2 * H, d = base + 3 * H;
    const bool va = (base < H);
    const bool vb = va && (b < N);
    const bool vc = va && (c < N);
    const bool vd = va && (d < N);

    float ax0 = 0.f, ay0 = 0.f, az0 = 0.f, ax1 = 0.f, ay1 = 0.f, az1 = 0.f;
    if (va) { const float* p = bx + (size_t)a * 6;
        ax0 = p[0]; ay0 = p[1]; az0 = p[2]; ax1 = p[3]; ay1 = p[4]; az1 = p[5]; }
    float bx0 = 0.f, by0 = 0.f, bz0 = 0.f, bx1 = 0.f, by1 = 0.f, bz1 = 0.f;
    if (vb) { const float* p = bx + (size_t)b * 6;
        bx0 = p[0]; by0 = p[1]; bz0 = p[2]; bx1 = p[3]; by1 = p[4]; bz1 = p[5]; }
    float cx0 = 0.f, cy0 = 0.f, cz0 = 0.f, cx1 = 0.f, cy1 = 0.f, cz1 = 0.f;
    if (vc) { const float* p = bx + (size_t)c * 6;
        cx0 = p[0]; cy0 = p[1]; cz0 = p[2]; cx1 = p[3]; cy1 = p[4]; cz1 = p[5]; }
    float dx0 = 0.f, dy0 = 0.f, dz0 = 0.f, dx1 = 0.f, dy1 = 0.f, dz1 = 0.f;
    if (vd) { const float* p = bx + (size_t)d * 6;
        dx0 = p[0]; dy0 = p[1]; dz0 = p[2]; dx1 = p[3]; dy1 = p[4]; dz1 = p[5]; }

    const float a1a = __fmul_rn(__fmul_rn(__fsub_rn(ax1, ax0),
                       __fsub_rn(ay1, ay0)), __fsub_rn(az1, az0));
    const float a1b = __fmul_rn(__fmul_rn(__fsub_rn(bx1, bx0),
                       __fsub_rn(by1, by0)), __fsub_rn(bz1, bz0));
    const float a1c = __fmul_rn(__fmul_rn(__fsub_rn(cx1, cx0),
                       __fsub_rn(cy1, cy0)), __fsub_rn(cz1, cz0));
    const float a1d = __fmul_rn(__fmul_rn(__fsub_rn(dx1, dx0),
                       __fsub_rn(dy1, dy0)), __fsub_rn(dz1, dz0));

    const unsigned encA = 0xFFFFFFFFu - (unsigned)a;   // loop-invariant
    const unsigned encB = 0xFFFFFFFFu - (unsigned)b;
    const unsigned encC = 0xFFFFFFFFu - (unsigned)c;
    const unsigned encD = 0xFFFFFFFFu - (unsigned)d;

    // ---- this wave's gt chunk ----
    const int chunk = (M + 3) >> 2;
    const int g0 = wv * chunk;
    const int g1 = (g0 + chunk < M) ? (g0 + chunk) : M;

    float bestA = 0.f, bestB = 0.f, bestC = 0.f, bestD = 0.f;
    int   argA = g0,   argB = g0,   argC = g0,   argD = g0;

    // ---- g-loop, 4 gts per iteration: 8 batched ds_read_b128, then 16
    //      register-resident IoU chains (one lgkmcnt wait per 4 gts) ----
    int g = g0;
    for (; g + 3 < g1; g += 4) {
        const float4 glo0 = gb4[2*g+0], ghi0 = gb4[2*g+1];
        const float4 glo1 = gb4[2*g+2], ghi1 = gb4[2*g+3];
        const float4 glo2 = gb4[2*g+4], ghi2 = gb4[2*g+5];
        const float4 glo3 = gb4[2*g+6], ghi3 = gb4[2*g+7];
        IOU_G(glo0, ghi0, g + 0)
        IOU_G(glo1, ghi1, g + 1)
        IOU_G(glo2, ghi2, g + 2)
        IOU_G(glo3, ghi3, g + 3)
    }
    for (; g < g1; ++g) {                    // tail (never taken at M=128)
        const float4 glo = gb4[2*g], ghi = gb4[2*g+1];
        IOU_G(glo, ghi, g)
    }

    // ---- merge per-anchor chunk results: (iou_bits<<32)|~g, max = best iou,
    //      smallest g on ties (first-index argmax across the full 0..M-1) ----
    if (va) atomicMax(&asl[0 * 64 + lane],
        ((unsigned long long)__float_as_uint(bestA) << 32) |
        (unsigned long long)(0xFFFFFFFFu - (unsigned)argA));
    if (vb) atomicMax(&asl[1 * 64 + lane],
        ((unsigned long long)__float_as_uint(bestB) << 32) |
        (unsigned long long)(0xFFFFFFFFu - (unsigned)argB));
    if (vc) atomicMax(&asl[2 * 64 + lane],
        ((unsigned long long)__float_as_uint(bestC) << 32) |
        (unsigned long long)(0xFFFFFFFFu - (unsigned)argC));
    if (vd) atomicMax(&asl[3 * 64 + lane],
        ((unsigned long long)__float_as_uint(bestD) << 32) |
        (unsigned long long)(0xFFFFFFFFu - (unsigned)argD));
    __syncthreads();

    // ---- flush per-gt maxima to global slots ----
    if (tid < M) {
        unsigned long long v = lsl[tid];
        if (v) atomicMax(&slots[tid], v);
    }

    // ---- epilogue: thread tid owns anchor slot tid ----
    {
        const int k = tid >> 6, l = tid & 63;
        const int sb = blockIdx.x * 64 + l;
        const int anchor = sb + k * H;
        if (sb < H && anchor < N) {
            const unsigned long long v = asl[tid];
            const float best = __uint_as_float((unsigned)(v >> 32));
            const int garg = (int)(0xFFFFFFFFu - (unsigned)(v & 0xFFFFFFFFu));
            const float* gbf = (const float*)gb4;   // [8g+0..5]=box +6=area +7=label
            float lab;
            if (best >= 0.7f) lab = gbf[8 * garg + 7];
            else              lab = (best < 0.3f) ? 0.f : -1.f;
            out_lab[anchor] = lab;
            float* ob = out_bb + (size_t)anchor * 6;
            if (best >= 0.7f) {
                ob[0] = gbf[8*garg+0]; ob[1] = gbf[8*garg+1]; ob[2] = gbf[8*garg+2];
                ob[3] = gbf[8*garg+3]; ob[4] = gbf[8*garg+4]; ob[5] = gbf[8*garg+5];
            } else {
                ob[0] = -1.f; ob[1] = -1.f; ob[2] = -1.f;
                ob[3] = -1.f; ob[4] = -1.f; ob[5] = -1.f;
            }
        }
    }
}

// Low-quality override (separate dispatch — fusing this tail provably makes
// hipcc spill the main loop's live set, R3-R8): for each gt with a nonzero
// slot (column max >= 0.3), its argmax anchor gets that gt; when several gts
// pick the same anchor the LARGEST gt index wins (.at[].max scatter).
__global__ __launch_bounds__(MMAX) void iou_override(
    const float* __restrict__ gt, const int* __restrict__ gl,
    const unsigned long long* __restrict__ slots,
    float* __restrict__ out_lab, float* __restrict__ out_bb, int M)
{
    __shared__ int s_anchor[MMAX];
    __shared__ int s_cand[MMAX];
    const int i = threadIdx.x;

    int anchor = -1, cand = 0;
    if (i < M) {
        unsigned long long v = slots[i];
        if (v != 0ULL) {               // gt_iou_max >= 0.3 (gated at insert)
            anchor = (int)(0xFFFFFFFFu - (unsigned)(v & 0xFFFFFFFFu));
            cand   = i + 1;
        }
    }
    s_anchor[i] = anchor;
    s_cand[i]   = cand;
    __syncthreads();

    if (cand > 0) {
        bool win = true;
        for (int j = 0; j < M; ++j)
            if (s_cand[j] > cand && s_anchor[j] == anchor) { win = false; break; }
        if (win) {
            out_lab[anchor] = (float)gl[i];
            float* ob = out_bb + (size_t)anchor * 6;
            const float* gp = gt + (size_t)i * 6;
            ob[0] = gp[0]; ob[1] = gp[1]; ob[2] = gp[2];
            ob[3] = gp[3]; ob[4] = gp[4]; ob[5] = gp[5];
        }
    }
}

extern "C" void kernel_launch(void* const* d_in, const int* in_sizes, int n_in,
                              void* d_out, int out_size, void* d_ws, size_t ws_size,
                              hipStream_t stream)
{
    const float* bx = (const float*)d_in[0];
    const float* gt = (const float*)d_in[1];
    const int*   gl = (const int*)d_in[2];
    const int N = in_sizes[0] / 6;
    int M = in_sizes[1] / 6;
    if (M > MMAX) M = MMAX;

    float* out_lab = (float*)d_out;
    float* out_bb  = (float*)d_out + N;

    unsigned long long* slots = (unsigned long long*)d_ws;

    // slots MUST be re-zeroed every call (ws is poisoned once, not re-poisoned
    // between timed replays; first correctness call sees arbitrary ws).
    hipMemsetAsync(d_ws, 0, MMAX * 8, stream);

    const int H = (N + 3) / 4;
    const int nblocks = (H + 63) / 64;

    if (M == MMAX) {
        hipLaunchKernelGGL(iou_main<MMAX>, dim3(nblocks), dim3(256), 0, stream,
                           bx, gt, gl, out_lab, out_bb, slots, N, M);
    } else {
        hipLaunchKernelGGL(iou_main<0>, dim3(nblocks), dim3(256), 0, stream,
                           bx, gt, gl, out_lab, out_bb, slots, N, M);
    }
    hipLaunchKernelGGL(iou_override, dim3(1), dim3(MMAX), 0, stream,
                       gt, gl, slots, out_lab, out_bb, M);
}